// Round 3
// baseline (1321.704 us; speedup 1.0000x reference)
//
#include <hip/hip_runtime.h>

typedef unsigned short u16;
typedef __bf16 bf16x8 __attribute__((ext_vector_type(8)));
typedef float f32x4 __attribute__((ext_vector_type(4)));

__device__ __forceinline__ float b2f(u16 h) {
    union { unsigned int u; float f; } x; x.u = ((unsigned int)h) << 16; return x.f;
}
__device__ __forceinline__ u16 f2b(float f) {
    union { float f; unsigned int u; } x; x.f = f;
    unsigned int u = x.u;
    unsigned int r = (u + 0x7FFFu + ((u >> 16) & 1u)) >> 16;
    return (u16)r;
}
// dual-dtype scalar load -> f32
__device__ __forceinline__ float ldf(const void* p, size_t i, int fl) {
    return fl ? ((const float*)p)[i] : b2f(((const u16*)p)[i]);
}
__device__ __forceinline__ float wave_sum(float v) {
#pragma unroll
    for (int off = 32; off > 0; off >>= 1) v += __shfl_down(v, off, 64);
    return v;
}
__device__ __forceinline__ float wave_max(float v) {
#pragma unroll
    for (int off = 32; off > 0; off >>= 1) v = fmaxf(v, __shfl_down(v, off, 64));
    return v;
}
__device__ __forceinline__ int wave_scan_incl(int v, int lane) {
#pragma unroll
    for (int off = 1; off < 64; off <<= 1) {
        int n = __shfl_up(v, off, 64);
        if (lane >= off) v += n;
    }
    return v;
}

// ---------------- dtype detect: edge_val in [0,1). bf16 data -> low u16 of
// every aliased u32 is a bf16 in [0,1]; f32 data -> random mantissa bits. ----
__global__ void k_detect(const void* __restrict__ evalraw, int* __restrict__ flag, int E) {
    const unsigned int* w = (const unsigned int*)evalraw;
    int nw = E / 2;                       // words safely readable in BOTH modes
    int stride = nw / 1024; if (stride < 1) stride = 1;
    int bad = 0;
    for (int j = 0; j < 4; ++j) {
        int idx = (threadIdx.x * 4 + j) * stride;
        if (idx < nw) {
            u16 lo = (u16)(w[idx] & 0xFFFFu);
            float f = b2f(lo);
            if (!(f >= 0.0f && f <= 1.0f)) bad = 1;
        }
    }
    __shared__ int sbad;
    if (threadIdx.x == 0) sbad = 0;
    __syncthreads();
    if (bad) atomicAdd(&sbad, 1);
    __syncthreads();
    if (threadIdx.x == 0) flag[0] = (sbad > 0) ? 1 : 0;   // 1 = f32 inputs
}

// ---------------- weight pack: Wt[n][k] = [Wself|Wnb][k][n], bf16 -----------
__global__ void k_pack(const void* __restrict__ Ws1, const void* __restrict__ Wn1,
                       const void* __restrict__ Ws2, const void* __restrict__ Wn2,
                       u16* __restrict__ Wt1, u16* __restrict__ Wt2,
                       const int* __restrict__ flagp) {
    int fl = flagp[0];
    int k = blockIdx.x & 255;
    int layer = blockIdx.x >> 8;
    int n = threadIdx.x;
    const void* Ws = layer ? Ws2 : Ws1;
    const void* Wn = layer ? Wn2 : Wn1;
    u16* Wt = layer ? Wt2 : Wt1;
    Wt[n * 256 + k] = f2b(ldf(Ws, (size_t)k * 256 + n, fl));
    Wt[(n + 256) * 256 + k] = f2b(ldf(Wn, (size_t)k * 256 + n, fl));
}

// ---------------- pack small tensors into canonical bf16 ---------------------
// layout: 0:b1[256] 256:b2[256] 512:g1w[256] 768:g2w[256] 1024:g1b 1025:g2b
//         1026:e2pb[128] 1280:e2pw[32768]  total 34048
__global__ void k_smalls(const void* b1, const void* b2v, const void* g1w,
                         const void* g2w, const void* g1b, const void* g2b,
                         const void* e2pw, const void* e2pb,
                         u16* __restrict__ sm, const int* __restrict__ flagp) {
    int fl = flagp[0];
    int i = blockIdx.x * 256 + threadIdx.x;
    if (i >= 34048) return;
    float v = 0.f;
    if (i < 256)        v = ldf(b1, i, fl);
    else if (i < 512)   v = ldf(b2v, i - 256, fl);
    else if (i < 768)   v = ldf(g1w, i - 512, fl);
    else if (i < 1024)  v = ldf(g2w, i - 768, fl);
    else if (i == 1024) v = ldf(g1b, 0, fl);
    else if (i == 1025) v = ldf(g2b, 0, fl);
    else if (i < 1154)  v = ldf(e2pb, i - 1026, fl);
    else if (i >= 1280) v = ldf(e2pw, i - 1280, fl);
    sm[i] = f2b(v);
}

// ---------------- CSR build --------------------------------------------------
__global__ void k_hist(const int* __restrict__ row, int* __restrict__ deg, int E, int N) {
    int t = blockIdx.x * 256 + threadIdx.x;
    if (t < E) {
        int r = row[t];
        if ((unsigned)r < (unsigned)N) atomicAdd(&deg[r], 1);
    }
}

__global__ void k_scan1(const int* __restrict__ deg, int* __restrict__ rowptr,
                        int* __restrict__ bsum, int N) {
    int tid = threadIdx.x;
    int t = blockIdx.x * 256 + tid;
    int lane = tid & 63, w = tid >> 6;
    int v = (t < N) ? deg[t] : 0;
    int inc = wave_scan_incl(v, lane);
    __shared__ int wsum[4];
    if (lane == 63) wsum[w] = inc;
    __syncthreads();
    int woff = 0;
#pragma unroll
    for (int j = 0; j < 4; ++j) if (j < w) woff += wsum[j];
    if (t < N) rowptr[t] = woff + inc - v;
    if (tid == 255) bsum[blockIdx.x] = woff + inc;
}

__global__ void k_scan2(int* __restrict__ bsum, int nb) {  // 1 block, 512 thr
    int tid = threadIdx.x;
    int lane = tid & 63, w = tid >> 6;
    int v = (tid < nb) ? bsum[tid] : 0;
    int inc = wave_scan_incl(v, lane);
    __shared__ int wsum[8];
    if (lane == 63) wsum[w] = inc;
    __syncthreads();
    int woff = 0;
#pragma unroll
    for (int j = 0; j < 8; ++j) if (j < w) woff += wsum[j];
    if (tid < nb) bsum[tid] = woff + inc - v;
}

__global__ void k_scan3(const int* __restrict__ bsum, int* __restrict__ rowptr,
                        int* __restrict__ cursor, int N, int E) {
    int t = blockIdx.x * 256 + threadIdx.x;
    if (t < N) {
        int v = rowptr[t] + bsum[blockIdx.x];
        rowptr[t] = v;
        cursor[t] = v;
    }
    if (blockIdx.x == 0 && threadIdx.x == 0) rowptr[N] = E;
}

__global__ void k_scatter(const int* __restrict__ row, const int* __restrict__ col,
                          const void* __restrict__ val, int* __restrict__ cursor,
                          int* __restrict__ scol, float* __restrict__ sval,
                          int E, int N, const int* __restrict__ flagp) {
    int fl = flagp[0];
    int t = blockIdx.x * 256 + threadIdx.x;
    if (t < E) {
        int r = row[t];
        if ((unsigned)r >= (unsigned)N) return;
        int pos = atomicAdd(&cursor[r], 1);
        if ((unsigned)pos < (unsigned)E) {
            scol[pos] = col[t];
            sval[pos] = ldf(val, t, fl);
        }
    }
}

// ---------------- GEMM: C[M,512] = A[M,256] @ Wt[512,256]^T (bf16, f32 acc) --
// adual: A may be f32 (per runtime flag); r-scale optionally fused in epilogue
__global__ __launch_bounds__(256) void k_gemm(const void* __restrict__ Araw,
                                              const u16* __restrict__ Wt,
                                              u16* __restrict__ C, int M,
                                              const float* __restrict__ l1s,
                                              const float* __restrict__ scrf,
                                              const int* __restrict__ flagp,
                                              int adual) {
    const int tid = threadIdx.x;
    const int lane = tid & 63;
    const int wid = tid >> 6;
    const int mbase = blockIdx.x * 128;
    const int nbase = blockIdx.y * 128;
    const int wm = (wid >> 1) * 64;
    const int wn = (wid & 1) * 64;
    const int fl = adual ? flagp[0] : 0;

    __shared__ __align__(16) u16 As[128][72];
    __shared__ __align__(16) u16 Bs[128][72];

    f32x4 acc[4][4];
#pragma unroll
    for (int a = 0; a < 4; ++a)
#pragma unroll
        for (int b = 0; b < 4; ++b) acc[a][b] = (f32x4){0.f, 0.f, 0.f, 0.f};

    const u16* Ah = (const u16*)Araw;
    const float* Af = (const float*)Araw;

    for (int ks = 0; ks < 4; ++ks) {
        const int kbase = ks * 64;
#pragma unroll
        for (int c = 0; c < 4; ++c) {
            int cidx = tid + 256 * c;      // 0..1023
            int row = cidx >> 3;
            int cc = cidx & 7;
            int grow = mbase + row;
            uint4 va = {0u, 0u, 0u, 0u};
            if (grow < M) {
                size_t off = (size_t)grow * 256 + kbase + cc * 8;
                if (fl) {
                    float4 fa = *(const float4*)(Af + off);
                    float4 fb = *(const float4*)(Af + off + 4);
                    va.x = (unsigned)f2b(fa.x) | ((unsigned)f2b(fa.y) << 16);
                    va.y = (unsigned)f2b(fa.z) | ((unsigned)f2b(fa.w) << 16);
                    va.z = (unsigned)f2b(fb.x) | ((unsigned)f2b(fb.y) << 16);
                    va.w = (unsigned)f2b(fb.z) | ((unsigned)f2b(fb.w) << 16);
                } else {
                    va = *(const uint4*)(Ah + off);
                }
            }
            *(uint4*)(&As[row][cc * 8]) = va;
            uint4 vb = *(const uint4*)(Wt + (size_t)(nbase + row) * 256 + kbase + cc * 8);
            *(uint4*)(&Bs[row][cc * 8]) = vb;
        }
        __syncthreads();
#pragma unroll
        for (int kk = 0; kk < 2; ++kk) {
            const int kof = kk * 32 + (lane >> 4) * 8;
            bf16x8 af[4], bfr[4];
#pragma unroll
            for (int mi = 0; mi < 4; ++mi)
                af[mi] = *(const bf16x8*)(&As[wm + mi * 16 + (lane & 15)][kof]);
#pragma unroll
            for (int ni = 0; ni < 4; ++ni)
                bfr[ni] = *(const bf16x8*)(&Bs[wn + ni * 16 + (lane & 15)][kof]);
#pragma unroll
            for (int mi = 0; mi < 4; ++mi)
#pragma unroll
                for (int ni = 0; ni < 4; ++ni)
                    acc[mi][ni] = __builtin_amdgcn_mfma_f32_16x16x32_bf16(
                        af[mi], bfr[ni], acc[mi][ni], 0, 0, 0);
        }
        __syncthreads();
    }

    const bool rs = (l1s != nullptr);
    const float M1 = rs ? scrf[0] : 0.f;
    const float inv1 = rs ? scrf[2] : 1.f;
#pragma unroll
    for (int mi = 0; mi < 4; ++mi) {
#pragma unroll
        for (int r = 0; r < 4; ++r) {
            int row = mbase + wm + mi * 16 + (lane >> 4) * 4 + r;
            if (row < M) {
                float scale = rs ? (__expf(l1s[row] - M1) * inv1) : 1.f;
#pragma unroll
                for (int ni = 0; ni < 4; ++ni) {
                    int col = nbase + wn + ni * 16 + (lane & 15);
                    C[(size_t)row * 512 + col] = f2b(acc[mi][ni][r] * scale);
                }
            }
        }
    }
}

// ---------------- layer-1 aggregation, fused relu epilogue -------------------
__global__ __launch_bounds__(256) void k_agg1(const u16* __restrict__ Ccat,
                                              const int* __restrict__ rowptr,
                                              const int* __restrict__ scol,
                                              const float* __restrict__ sval,
                                              const u16* __restrict__ bias,
                                              u16* __restrict__ Xout, int N, int E) {
    const int lane = threadIdx.x & 63;
    const int i = (int)((blockIdx.x * 256 + threadIdx.x) >> 6);
    if (i >= N) return;
    int s = rowptr[i], e = rowptr[i + 1];
    s = max(s, 0); e = min(e, E); if (e < s) e = s;
    float a0 = 0, a1 = 0, a2 = 0, a3 = 0;
    int k = s;
    for (; k + 4 <= e; k += 4) {
        int c0 = scol[k], c1 = scol[k + 1], c2 = scol[k + 2], c3 = scol[k + 3];
        c0 = ((unsigned)c0 < (unsigned)N) ? c0 : 0;
        c1 = ((unsigned)c1 < (unsigned)N) ? c1 : 0;
        c2 = ((unsigned)c2 < (unsigned)N) ? c2 : 0;
        c3 = ((unsigned)c3 < (unsigned)N) ? c3 : 0;
        float v0 = sval[k], v1 = sval[k + 1], v2 = sval[k + 2], v3 = sval[k + 3];
        ushort4 s0 = *(const ushort4*)(Ccat + (size_t)c0 * 512 + 256 + lane * 4);
        ushort4 s1 = *(const ushort4*)(Ccat + (size_t)c1 * 512 + 256 + lane * 4);
        ushort4 s2 = *(const ushort4*)(Ccat + (size_t)c2 * 512 + 256 + lane * 4);
        ushort4 s3 = *(const ushort4*)(Ccat + (size_t)c3 * 512 + 256 + lane * 4);
        a0 += v0 * b2f(s0.x) + v1 * b2f(s1.x) + v2 * b2f(s2.x) + v3 * b2f(s3.x);
        a1 += v0 * b2f(s0.y) + v1 * b2f(s1.y) + v2 * b2f(s2.y) + v3 * b2f(s3.y);
        a2 += v0 * b2f(s0.z) + v1 * b2f(s1.z) + v2 * b2f(s2.z) + v3 * b2f(s3.z);
        a3 += v0 * b2f(s0.w) + v1 * b2f(s1.w) + v2 * b2f(s2.w) + v3 * b2f(s3.w);
    }
    for (; k < e; ++k) {
        int c = scol[k];
        c = ((unsigned)c < (unsigned)N) ? c : 0;
        float v = sval[k];
        ushort4 sp = *(const ushort4*)(Ccat + (size_t)c * 512 + 256 + lane * 4);
        a0 += v * b2f(sp.x); a1 += v * b2f(sp.y);
        a2 += v * b2f(sp.z); a3 += v * b2f(sp.w);
    }
    ushort4 se = *(const ushort4*)(Ccat + (size_t)i * 512 + lane * 4);
    ushort4 bb = *(const ushort4*)(bias + lane * 4);
    float o0 = b2f(se.x) + a0 + b2f(bb.x); o0 = o0 > 0.f ? o0 : 0.f;
    float o1 = b2f(se.y) + a1 + b2f(bb.y); o1 = o1 > 0.f ? o1 : 0.f;
    float o2 = b2f(se.z) + a2 + b2f(bb.z); o2 = o2 > 0.f ? o2 : 0.f;
    float o3 = b2f(se.w) + a3 + b2f(bb.w); o3 = o3 > 0.f ? o3 : 0.f;
    if (!__builtin_isfinite(o0)) o0 = 0.f;
    if (!__builtin_isfinite(o1)) o1 = 0.f;
    if (!__builtin_isfinite(o2)) o2 = 0.f;
    if (!__builtin_isfinite(o3)) o3 = 0.f;
    ushort4 ov; ov.x = f2b(o0); ov.y = f2b(o1); ov.z = f2b(o2); ov.w = f2b(o3);
    *(ushort4*)(Xout + (size_t)i * 256 + lane * 4) = ov;
}

// ---------------- gate logits + block max ------------------------------------
__global__ __launch_bounds__(256) void k_gates1(
    const u16* __restrict__ Xbuf, const u16* __restrict__ g1w, const u16* __restrict__ g1b,
    const u16* __restrict__ g2w, const u16* __restrict__ g2b,
    float* __restrict__ l1, float* __restrict__ l2,
    float* __restrict__ pm1, float* __restrict__ pm2, int N) {
    const int tid = threadIdx.x;
    const int lane = tid & 63, w = tid >> 6;
    ushort4 w1 = *(const ushort4*)(g1w + lane * 4);
    ushort4 w2 = *(const ushort4*)(g2w + lane * 4);
    float w10 = b2f(w1.x), w11 = b2f(w1.y), w12 = b2f(w1.z), w13 = b2f(w1.w);
    float w20 = b2f(w2.x), w21 = b2f(w2.y), w22 = b2f(w2.z), w23 = b2f(w2.w);
    float bb1 = b2f(g1b[0]), bb2 = b2f(g2b[0]);
    float m1 = -1e30f, m2 = -1e30f;
    for (int i = blockIdx.x * 4 + w; i < N; i += gridDim.x * 4) {
        ushort4 xv = *(const ushort4*)(Xbuf + (size_t)i * 256 + lane * 4);
        float x0 = b2f(xv.x), x1 = b2f(xv.y), x2 = b2f(xv.z), x3 = b2f(xv.w);
        float p1 = x0 * w10 + x1 * w11 + x2 * w12 + x3 * w13;
        float p2 = x0 * w20 + x1 * w21 + x2 * w22 + x3 * w23;
        p1 = wave_sum(p1); p2 = wave_sum(p2);
        if (lane == 0) {
            float v1 = p1 + bb1, v2 = p2 + bb2;
            l1[i] = v1; l2[i] = v2;
            m1 = fmaxf(m1, v1); m2 = fmaxf(m2, v2);
        }
    }
    __shared__ float s1[4], s2[4];
    if (lane == 0) { s1[w] = m1; s2[w] = m2; }
    __syncthreads();
    if (tid == 0) {
        pm1[blockIdx.x] = fmaxf(fmaxf(s1[0], s1[1]), fmaxf(s1[2], s1[3]));
        pm2[blockIdx.x] = fmaxf(fmaxf(s2[0], s2[1]), fmaxf(s2[2], s2[3]));
    }
}

__global__ void k_gmax(const float* __restrict__ pm1, const float* __restrict__ pm2,
                       float* __restrict__ scrf) {  // 1 block, 256 thr
    int tid = threadIdx.x;
    int lane = tid & 63, w = tid >> 6;
    float r1 = wave_max(pm1[tid]);
    float r2 = wave_max(pm2[tid]);
    __shared__ float s1[4], s2[4];
    if (lane == 0) { s1[w] = r1; s2[w] = r2; }
    __syncthreads();
    if (tid == 0) {
        scrf[0] = fmaxf(fmaxf(s1[0], s1[1]), fmaxf(s1[2], s1[3]));
        scrf[1] = fmaxf(fmaxf(s2[0], s2[1]), fmaxf(s2[2], s2[3]));
    }
}

__global__ __launch_bounds__(256) void k_gexp(const float* __restrict__ l1,
                                              const float* __restrict__ l2,
                                              const float* __restrict__ scrf,
                                              float* __restrict__ ps1,
                                              float* __restrict__ ps2, int N) {
    int tid = threadIdx.x;
    int lane = tid & 63, w = tid >> 6;
    float M1 = scrf[0], M2 = scrf[1];
    float a1 = 0.f, a2 = 0.f;
    for (int i = blockIdx.x * 256 + tid; i < N; i += 256 * 256) {
        a1 += __expf(l1[i] - M1);
        a2 += __expf(l2[i] - M2);
    }
    a1 = wave_sum(a1); a2 = wave_sum(a2);
    __shared__ float s1[4], s2[4];
    if (lane == 0) { s1[w] = a1; s2[w] = a2; }
    __syncthreads();
    if (tid == 0) {
        ps1[blockIdx.x] = s1[0] + s1[1] + s1[2] + s1[3];
        ps2[blockIdx.x] = s2[0] + s2[1] + s2[2] + s2[3];
    }
}

__global__ void k_gsum(const float* __restrict__ ps1, const float* __restrict__ ps2,
                       float* __restrict__ scrf) {  // 1 block, 256 thr
    int tid = threadIdx.x;
    int lane = tid & 63, w = tid >> 6;
    float r1 = wave_sum(ps1[tid]);
    float r2 = wave_sum(ps2[tid]);
    __shared__ float s1[4], s2[4];
    if (lane == 0) { s1[w] = r1; s2[w] = r2; }
    __syncthreads();
    if (tid == 0) {
        scrf[2] = 1.0f / (s1[0] + s1[1] + s1[2] + s1[3]);
        scrf[3] = 1.0f / (s2[0] + s2[1] + s2[2] + s2[3]);
    }
}

// ---------------- layer-2 aggregation + gated combine + column mean ----------
__global__ __launch_bounds__(256) void k_agg2(const u16* __restrict__ Ccat,
                                              const int* __restrict__ rowptr,
                                              const int* __restrict__ scol,
                                              const float* __restrict__ sval,
                                              const u16* __restrict__ bias,
                                              const u16* __restrict__ Xbuf,
                                              const float* __restrict__ l2,
                                              const float* __restrict__ scrf,
                                              void* __restrict__ doutv,
                                              float* __restrict__ colsum, int N, int E,
                                              const int* __restrict__ flagp) {
    const int fl = flagp[0];
    const int tid = threadIdx.x;
    const int lane = tid & 63, w = tid >> 6;
    const int gw0 = blockIdx.x * 4 + w;
    const int nw = gridDim.x * 4;
    const float M2 = scrf[1], inv2 = scrf[3];
    float c0 = 0, c1 = 0, c2 = 0, c3 = 0;
    for (int i = gw0; i < N; i += nw) {
        int s = rowptr[i], e = rowptr[i + 1];
        s = max(s, 0); e = min(e, E); if (e < s) e = s;
        float a0 = 0, a1 = 0, a2 = 0, a3 = 0;
        int k = s;
        for (; k + 4 <= e; k += 4) {
            int q0 = scol[k], q1 = scol[k + 1], q2 = scol[k + 2], q3 = scol[k + 3];
            q0 = ((unsigned)q0 < (unsigned)N) ? q0 : 0;
            q1 = ((unsigned)q1 < (unsigned)N) ? q1 : 0;
            q2 = ((unsigned)q2 < (unsigned)N) ? q2 : 0;
            q3 = ((unsigned)q3 < (unsigned)N) ? q3 : 0;
            float v0 = sval[k], v1 = sval[k + 1], v2 = sval[k + 2], v3 = sval[k + 3];
            ushort4 s0 = *(const ushort4*)(Ccat + (size_t)q0 * 512 + 256 + lane * 4);
            ushort4 s1 = *(const ushort4*)(Ccat + (size_t)q1 * 512 + 256 + lane * 4);
            ushort4 s2 = *(const ushort4*)(Ccat + (size_t)q2 * 512 + 256 + lane * 4);
            ushort4 s3 = *(const ushort4*)(Ccat + (size_t)q3 * 512 + 256 + lane * 4);
            a0 += v0 * b2f(s0.x) + v1 * b2f(s1.x) + v2 * b2f(s2.x) + v3 * b2f(s3.x);
            a1 += v0 * b2f(s0.y) + v1 * b2f(s1.y) + v2 * b2f(s2.y) + v3 * b2f(s3.y);
            a2 += v0 * b2f(s0.z) + v1 * b2f(s1.z) + v2 * b2f(s2.z) + v3 * b2f(s3.z);
            a3 += v0 * b2f(s0.w) + v1 * b2f(s1.w) + v2 * b2f(s2.w) + v3 * b2f(s3.w);
        }
        for (; k < e; ++k) {
            int c = scol[k];
            c = ((unsigned)c < (unsigned)N) ? c : 0;
            float v = sval[k];
            ushort4 sp = *(const ushort4*)(Ccat + (size_t)c * 512 + 256 + lane * 4);
            a0 += v * b2f(sp.x); a1 += v * b2f(sp.y);
            a2 += v * b2f(sp.z); a3 += v * b2f(sp.w);
        }
        ushort4 se = *(const ushort4*)(Ccat + (size_t)i * 512 + lane * 4);
        ushort4 bb = *(const ushort4*)(bias + lane * 4);
        ushort4 xv = *(const ushort4*)(Xbuf + (size_t)i * 256 + lane * 4);
        float zi = __expf(l2[i] - M2) * inv2;
        float t0 = b2f(se.x) + a0 + b2f(bb.x); t0 = t0 > 0.f ? t0 : 0.f;
        float t1 = b2f(se.y) + a1 + b2f(bb.y); t1 = t1 > 0.f ? t1 : 0.f;
        float t2 = b2f(se.z) + a2 + b2f(bb.z); t2 = t2 > 0.f ? t2 : 0.f;
        float t3 = b2f(se.w) + a3 + b2f(bb.w); t3 = t3 > 0.f ? t3 : 0.f;
        float e0 = (1.f - zi) * b2f(xv.x) + zi * t0;
        float e1 = (1.f - zi) * b2f(xv.y) + zi * t1;
        float e2 = (1.f - zi) * b2f(xv.z) + zi * t2;
        float e3 = (1.f - zi) * b2f(xv.w) + zi * t3;
        if (!__builtin_isfinite(e0)) e0 = 0.f;
        if (!__builtin_isfinite(e1)) e1 = 0.f;
        if (!__builtin_isfinite(e2)) e2 = 0.f;
        if (!__builtin_isfinite(e3)) e3 = 0.f;
        if (fl) {
            float4 fv = {e0, e1, e2, e3};
            *(float4*)((float*)doutv + (size_t)i * 256 + lane * 4) = fv;
        } else {
            ushort4 ov; ov.x = f2b(e0); ov.y = f2b(e1); ov.z = f2b(e2); ov.w = f2b(e3);
            *(ushort4*)((u16*)doutv + (size_t)i * 256 + lane * 4) = ov;
        }
        c0 += e0; c1 += e1; c2 += e2; c3 += e3;
    }
    __shared__ float part[4][256];
    part[w][lane * 4 + 0] = c0;
    part[w][lane * 4 + 1] = c1;
    part[w][lane * 4 + 2] = c2;
    part[w][lane * 4 + 3] = c3;
    __syncthreads();
    float ssum = part[0][tid] + part[1][tid] + part[2][tid] + part[3][tid];
    atomicAdd(&colsum[tid], ssum);
}

// ---------------- readout ----------------------------------------------------
__global__ void k_final(const float* __restrict__ colsum, const u16* __restrict__ e2pw,
                        const u16* __restrict__ e2pb, void* __restrict__ doutv,
                        int N, const int* __restrict__ flagp) {  // 1 block, 128 thr
    int fl = flagp[0];
    int j = threadIdx.x;
    float invN = 1.0f / (float)N;
    float acc = b2f(e2pb[j]);
    for (int f = 0; f < 256; ++f)
        acc += colsum[f] * invN * b2f(e2pw[f * 128 + j]);
    if (!__builtin_isfinite(acc)) acc = 0.f;
    size_t off = (size_t)N * 256 + j;
    if (fl) ((float*)doutv)[off] = acc;
    else ((u16*)doutv)[off] = f2b(acc);
}

extern "C" void kernel_launch(void* const* d_in, const int* in_sizes, int n_in,
                              void* d_out, int out_size, void* d_ws, size_t ws_size,
                              hipStream_t stream) {
    (void)n_in; (void)out_size; (void)ws_size;
    const void* x_in   = d_in[0];
    const int* erow    = (const int*)d_in[1];
    const int* ecol    = (const int*)d_in[2];
    const void* evalr  = d_in[3];
    const void* Wself1 = d_in[4];
    const void* Wnb1   = d_in[5];
    const void* b1     = d_in[6];
    const void* Wself2 = d_in[7];
    const void* Wnb2   = d_in[8];
    const void* b2v    = d_in[9];
    const void* g1w    = d_in[10];
    const void* g1b    = d_in[11];
    const void* g2w    = d_in[12];
    const void* g2b    = d_in[13];
    const void* e2pw   = d_in[14];
    const void* e2pb   = d_in[15];

    const int N = in_sizes[0] / 256;   // 100000
    const int E = in_sizes[1];         // 3200000

    char* p = (char*)d_ws;
    auto alloc = [&](size_t bytes) {
        char* r = p;
        p += (bytes + 255) & ~((size_t)255);
        return r;
    };
    int*   flag   = (int*)alloc(256);
    int*   rowptr = (int*)alloc((size_t)(N + 1) * 4);
    int*   cursor = (int*)alloc((size_t)N * 4);
    int*   deg    = (int*)alloc((size_t)N * 4);
    float* l1     = (float*)alloc((size_t)N * 4);
    float* l2     = (float*)alloc((size_t)N * 4);
    int*   bsum   = (int*)alloc(4096);
    float* pm1    = (float*)alloc(1024);
    float* pm2    = (float*)alloc(1024);
    float* ps1    = (float*)alloc(1024);
    float* ps2    = (float*)alloc(1024);
    float* scrf   = (float*)alloc(256);
    float* colsum = (float*)alloc(1024);
    u16*   Wt1    = (u16*)alloc((size_t)512 * 256 * 2);
    u16*   Wt2    = (u16*)alloc((size_t)512 * 256 * 2);
    u16*   sm     = (u16*)alloc((size_t)34048 * 2);
    int*   scol   = (int*)alloc((size_t)E * 4);
    float* sval   = (float*)alloc((size_t)E * 4);
    u16*   Xbuf   = (u16*)alloc((size_t)N * 256 * 2);
    u16*   Ccat   = (u16*)alloc((size_t)N * 512 * 2);   // biggest last

    hipMemsetAsync(deg, 0, (size_t)N * 4, stream);
    hipMemsetAsync(colsum, 0, 1024, stream);

    k_detect<<<1, 256, 0, stream>>>(evalr, flag, E);
    k_pack<<<512, 256, 0, stream>>>(Wself1, Wnb1, Wself2, Wnb2, Wt1, Wt2, flag);
    k_smalls<<<133, 256, 0, stream>>>(b1, b2v, g1w, g2w, g1b, g2b, e2pw, e2pb, sm, flag);

    int ebl = (E + 255) / 256;
    int nbl = (N + 255) / 256;
    k_hist<<<ebl, 256, 0, stream>>>(erow, deg, E, N);
    k_scan1<<<nbl, 256, 0, stream>>>(deg, rowptr, bsum, N);
    k_scan2<<<1, 512, 0, stream>>>(bsum, nbl);
    k_scan3<<<nbl, 256, 0, stream>>>(bsum, rowptr, cursor, N, E);
    k_scatter<<<ebl, 256, 0, stream>>>(erow, ecol, evalr, cursor, scol, sval, E, N, flag);

    dim3 gg((N + 127) / 128, 4);
    k_gemm<<<gg, 256, 0, stream>>>(x_in, Wt1, Ccat, N, nullptr, nullptr, flag, 1);

    int awb = (N * 64 + 255) / 256;   // one wave per node
    k_agg1<<<awb, 256, 0, stream>>>(Ccat, rowptr, scol, sval, sm + 0, Xbuf, N, E);

    k_gates1<<<256, 256, 0, stream>>>(Xbuf, sm + 512, sm + 1024, sm + 768, sm + 1025,
                                      l1, l2, pm1, pm2, N);
    k_gmax<<<1, 256, 0, stream>>>(pm1, pm2, scrf);
    k_gexp<<<256, 256, 0, stream>>>(l1, l2, scrf, ps1, ps2, N);
    k_gsum<<<1, 256, 0, stream>>>(ps1, ps2, scrf);

    k_gemm<<<gg, 256, 0, stream>>>(Xbuf, Wt2, Ccat, N, l1, scrf, flag, 0);
    k_agg2<<<4096, 256, 0, stream>>>(Ccat, rowptr, scol, sval, sm + 256, Xbuf, l2, scrf,
                                     d_out, colsum, N, E, flag);
    k_final<<<1, 128, 0, stream>>>(colsum, sm + 1280, sm + 1026, d_out, N, flag);
}